// Round 1
// baseline (2056.238 us; speedup 1.0000x reference)
//
#include <hip/hip_runtime.h>
#include <math.h>

#define E_DIM 128
#define NEAREST_SMAX 4096

// ---------------------------------------------------------------------------
// 1) nearest grid cell per off-grid point (L1 argmin, first-min tie-break)
// ---------------------------------------------------------------------------
__global__ void nearest_kernel(const float* __restrict__ xc_off, const float* __restrict__ xc_on,
                               int* __restrict__ nearest, int* __restrict__ counts, int U, int S) {
    __shared__ float2 on[NEAREST_SMAX];
    int b = blockIdx.y;
    const float2* onb = (const float2*)(xc_on + (size_t)b * S * 2);
    for (int i = threadIdx.x; i < S; i += blockDim.x) on[i] = onb[i];
    __syncthreads();
    int u = blockIdx.x * blockDim.x + threadIdx.x;
    if (u >= U) return;
    float2 p = ((const float2*)(xc_off + (size_t)b * U * 2))[u];
    float best = 3.402823466e38f;
    int bi = 0;
    for (int s = 0; s < S; ++s) {
        float d = fabsf(p.x - on[s].x) + fabsf(p.y - on[s].y);
        if (d < best) { best = d; bi = s; }
    }
    nearest[b * U + u] = bi;
    atomicAdd(&counts[b * S + bi], 1);
}

// ---------------------------------------------------------------------------
// 2) exclusive scan of counts -> CSR offsets (single block, N <= 16384)
// ---------------------------------------------------------------------------
__global__ void scan_kernel(const int* __restrict__ counts, int* __restrict__ offsets, int N) {
    __shared__ int part[1024];
    const int ITEMS = 16;
    int tid = threadIdx.x;
    int base = tid * ITEMS;
    int local[ITEMS];
    int sum = 0;
    for (int i = 0; i < ITEMS; ++i) {
        int idx = base + i;
        int v = (idx < N) ? counts[idx] : 0;
        local[i] = sum;
        sum += v;
    }
    part[tid] = sum;
    __syncthreads();
    for (int off = 1; off < 1024; off <<= 1) {
        int v = (tid >= off) ? part[tid - off] : 0;
        __syncthreads();
        part[tid] += v;
        __syncthreads();
    }
    int prev = (tid == 0) ? 0 : part[tid - 1];
    for (int i = 0; i < ITEMS; ++i) {
        int idx = base + i;
        if (idx < N) offsets[idx] = prev + local[i];
    }
    if (tid == blockDim.x - 1) offsets[N] = part[tid];
}

// ---------------------------------------------------------------------------
// 3) fill CSR token lists (order within a cell irrelevant: attention is
//    permutation-invariant over keys)
// ---------------------------------------------------------------------------
__global__ void fill_kernel(const int* __restrict__ nearest, const int* __restrict__ offsets,
                            int* __restrict__ cursor, int* __restrict__ tokens,
                            int BU, int U, int S) {
    int i = blockIdx.x * blockDim.x + threadIdx.x;
    if (i >= BU) return;
    int b = i / U;
    int u = i - b * U;
    int c = b * S + nearest[i];
    int pos = offsets[c] + atomicAdd(&cursor[c], 1);
    tokens[pos] = u;
}

// ---------------------------------------------------------------------------
// 4) row projections: C[M x 128] = A[M x 128] @ W[128 x 128], W in LDS
// ---------------------------------------------------------------------------
__global__ void proj_kernel(const float* __restrict__ A, const float* __restrict__ W,
                            float* __restrict__ C, int M) {
    __shared__ float Ws[E_DIM * E_DIM];
    for (int i = threadIdx.x; i < E_DIM * E_DIM; i += blockDim.x) Ws[i] = W[i];
    __syncthreads();
    int col = threadIdx.x & (E_DIM - 1);
    int rsub = threadIdx.x >> 7;   // 0..1 (wave-uniform row => scalar loads of a[e])
    int row0 = blockIdx.x * 64;
    int rend = min(row0 + 64, M);
    for (int r = row0 + rsub; r < rend; r += 2) {
        const float* a = A + (size_t)r * E_DIM;
        float acc = 0.f;
#pragma unroll
        for (int e = 0; e < E_DIM; ++e) acc += a[e] * Ws[e * E_DIM + col];
        C[(size_t)r * E_DIM + col] = acc;
    }
}

// same, but the input row is fake_embedding when *ignore_flag != 0
__global__ void proj_on_kernel(const float* __restrict__ Zon, const float* __restrict__ fake,
                               const int* __restrict__ ignore_flag,
                               const float* __restrict__ W, float* __restrict__ C, int M) {
    __shared__ float Ws[E_DIM * E_DIM];
    for (int i = threadIdx.x; i < E_DIM * E_DIM; i += blockDim.x) Ws[i] = W[i];
    __syncthreads();
    int ign = *ignore_flag;
    int col = threadIdx.x & (E_DIM - 1);
    int rsub = threadIdx.x >> 7;
    int row0 = blockIdx.x * 64;
    int rend = min(row0 + 64, M);
    for (int r = row0 + rsub; r < rend; r += 2) {
        const float* a = ign ? fake : (Zon + (size_t)r * E_DIM);
        float acc = 0.f;
#pragma unroll
        for (int e = 0; e < E_DIM; ++e) acc += a[e] * Ws[e * E_DIM + col];
        C[(size_t)r * E_DIM + col] = acc;
    }
}

// ---------------------------------------------------------------------------
// 5) per-cell masked MHA, 1 query, online softmax. One wave (64 lanes) per
//    cell. Lane l owns output elems l and l+64; head of elem l is l/16 (0..3),
//    head of elem l+64 is 4 + l/16. 16-lane shfl_xor butterfly gives each
//    group its head's dot product.
// ---------------------------------------------------------------------------
__global__ void attn_kernel(const float* __restrict__ Qpre,
                            const float* __restrict__ Koff, const float* __restrict__ Voff,
                            const float* __restrict__ Kon, const float* __restrict__ Von,
                            const int* __restrict__ offsets, const int* __restrict__ tokens,
                            float* __restrict__ AO, int S, int U) {
    int c = blockIdx.x;
    int b = c / S;
    int lane = threadIdx.x;  // 0..63
    float q0 = Qpre[(size_t)(c - b * S) * E_DIM + lane];
    float q1 = Qpre[(size_t)(c - b * S) * E_DIM + 64 + lane];
    float m1 = -INFINITY, l1 = 0.f, o0 = 0.f;
    float m2 = -INFINITY, l2 = 0.f, o1 = 0.f;
    int beg = offsets[c], end = offsets[c + 1];
    const float scale = 0.25f;  // 1/sqrt(dh), dh=16
    for (int t = beg; t <= end; ++t) {
        const float* kr;
        const float* vr;
        if (t < end) {
            int u = tokens[t];
            size_t rr = ((size_t)b * U + u) * E_DIM;
            kr = Koff + rr; vr = Voff + rr;
        } else {  // on-grid token (always valid, last slot)
            size_t rr = (size_t)c * E_DIM;
            kr = Kon + rr; vr = Von + rr;
        }
        float k0 = kr[lane], k1 = kr[64 + lane];
        float p0 = q0 * k0, p1 = q1 * k1;
#pragma unroll
        for (int off = 8; off >= 1; off >>= 1) {
            p0 += __shfl_xor(p0, off, 16);
            p1 += __shfl_xor(p1, off, 16);
        }
        float s1 = p0 * scale, s2 = p1 * scale;
        float v0 = vr[lane], v1 = vr[64 + lane];
        float nm = fmaxf(m1, s1);
        float f = __expf(m1 - nm), w = __expf(s1 - nm);
        l1 = l1 * f + w; o0 = o0 * f + w * v0; m1 = nm;
        nm = fmaxf(m2, s2);
        f = __expf(m2 - nm); w = __expf(s2 - nm);
        l2 = l2 * f + w; o1 = o1 * f + w * v1; m2 = nm;
    }
    AO[(size_t)c * E_DIM + lane] = o0 / l1;
    AO[(size_t)c * E_DIM + 64 + lane] = o1 / l2;
}

// ---------------------------------------------------------------------------
extern "C" void kernel_launch(void* const* d_in, const int* in_sizes, int n_in,
                              void* d_out, int out_size, void* d_ws, size_t ws_size,
                              hipStream_t stream) {
    const float* xc_off  = (const float*)d_in[0];
    const float* xc_on   = (const float*)d_in[1];
    const float* zc_off  = (const float*)d_in[2];
    const float* zc_on   = (const float*)d_in[3];
    const float* latents = (const float*)d_in[4];
    const float* fake    = (const float*)d_in[5];
    const float* Wq      = (const float*)d_in[6];
    const float* Wk      = (const float*)d_in[7];
    const float* Wv      = (const float*)d_in[8];
    const float* Wo      = (const float*)d_in[9];
    const int*   ignore  = (const int*)d_in[10];

    const int E = in_sizes[5];              // 128
    const int S = in_sizes[4] / E;          // 4096
    const int B = in_sizes[1] / (S * 2);    // 4
    const int U = in_sizes[0] / (B * 2);    // 4096
    const int BS = B * S, BU = B * U;

    char* ws = (char*)d_ws;
    size_t off = 0;
    auto alloc = [&](size_t bytes) {
        size_t r = off;
        off += (bytes + 255) & ~(size_t)255;
        return r;
    };
    int*   nearest = (int*)(ws + alloc((size_t)BU * 4));
    int*   counts  = (int*)(ws + alloc((size_t)BS * 4));
    int*   cursor  = (int*)(ws + alloc((size_t)BS * 4));
    int*   offsets = (int*)(ws + alloc((size_t)(BS + 1) * 4));
    int*   tokens  = (int*)(ws + alloc((size_t)BU * 4));
    float* Qpre    = (float*)(ws + alloc((size_t)S * E * 4));
    float* Koff    = (float*)(ws + alloc((size_t)BU * E * 4));
    float* Voff    = (float*)(ws + alloc((size_t)BU * E * 4));
    float* Kon     = (float*)(ws + alloc((size_t)BS * E * 4));
    float* Von     = (float*)(ws + alloc((size_t)BS * E * 4));
    float* AO      = (float*)(ws + alloc((size_t)BS * E * 4));

    hipMemsetAsync(counts, 0, (size_t)BS * 4, stream);
    hipMemsetAsync(cursor, 0, (size_t)BS * 4, stream);

    dim3 ngrid((U + 255) / 256, B);
    nearest_kernel<<<ngrid, 256, 0, stream>>>(xc_off, xc_on, nearest, counts, U, S);
    scan_kernel<<<1, 1024, 0, stream>>>(counts, offsets, BS);
    fill_kernel<<<(BU + 255) / 256, 256, 0, stream>>>(nearest, offsets, cursor, tokens, BU, U, S);

    proj_kernel<<<(S + 63) / 64, 256, 0, stream>>>(latents, Wq, Qpre, S);
    proj_kernel<<<(BU + 63) / 64, 256, 0, stream>>>(zc_off, Wk, Koff, BU);
    proj_kernel<<<(BU + 63) / 64, 256, 0, stream>>>(zc_off, Wv, Voff, BU);
    proj_on_kernel<<<(BS + 63) / 64, 256, 0, stream>>>(zc_on, fake, ignore, Wk, Kon, BS);
    proj_on_kernel<<<(BS + 63) / 64, 256, 0, stream>>>(zc_on, fake, ignore, Wv, Von, BS);

    attn_kernel<<<BS, 64, 0, stream>>>(Qpre, Koff, Voff, Kon, Von, offsets, tokens, AO, S, U);

    proj_kernel<<<(BS + 63) / 64, 256, 0, stream>>>(AO, Wo, (float*)d_out, BS);
}

// Round 2
// 281.051 us; speedup vs baseline: 7.3162x; 7.3162x over previous
//
#include <hip/hip_runtime.h>
#include <math.h>
#include <float.h>

#define E_DIM 128

// ---------------------------------------------------------------------------
// 1) nearest grid cell per off-grid point (L1 argmin, first-min tie-break).
//    Block = 256 threads = 64 u's x 4 S-partitions (each wave scans S/4 with
//    LDS-broadcast reads); lexicographic combine keeps jnp.argmin semantics.
// ---------------------------------------------------------------------------
__global__ void nearest_kernel(const float* __restrict__ xc_off, const float* __restrict__ xc_on,
                               int* __restrict__ nearest, int* __restrict__ counts, int U, int S) {
    __shared__ float2 on[4096];
    __shared__ float sh_d[4][64];
    __shared__ int   sh_i[4][64];
    int b = blockIdx.y;
    const float2* onb = (const float2*)(xc_on + (size_t)b * S * 2);
    for (int i = threadIdx.x; i < S; i += blockDim.x) on[i] = onb[i];
    __syncthreads();
    int ul = threadIdx.x & 63;
    int part = threadIdx.x >> 6;       // 0..3, wave-uniform
    int u = blockIdx.x * 64 + ul;
    float2 p = ((const float2*)(xc_off + (size_t)b * U * 2))[u];
    int qS = S >> 2;
    int s0 = part * qS, s1 = s0 + qS;
    float best = FLT_MAX;
    int bi = s0;
    for (int s = s0; s < s1; ++s) {
        float d = fabsf(p.x - on[s].x) + fabsf(p.y - on[s].y);
        if (d < best) { best = d; bi = s; }
    }
    sh_d[part][ul] = best;
    sh_i[part][ul] = bi;
    __syncthreads();
    if (part == 0) {
#pragma unroll
        for (int pp = 1; pp < 4; ++pp) {
            float d = sh_d[pp][ul];
            if (d < best) { best = d; bi = sh_i[pp][ul]; }  // strict < => earlier partition wins ties
        }
        nearest[b * U + u] = bi;
        atomicAdd(&counts[b * S + bi], 1);
    }
}

// ---------------------------------------------------------------------------
// 2) exclusive scan of counts -> CSR offsets (single block, N <= 16384)
// ---------------------------------------------------------------------------
__global__ void scan_kernel(const int* __restrict__ counts, int* __restrict__ offsets, int N) {
    __shared__ int part[1024];
    const int ITEMS = 16;
    int tid = threadIdx.x;
    int base = tid * ITEMS;
    int local[ITEMS];
    int sum = 0;
    for (int i = 0; i < ITEMS; ++i) {
        int idx = base + i;
        int v = (idx < N) ? counts[idx] : 0;
        local[i] = sum;
        sum += v;
    }
    part[tid] = sum;
    __syncthreads();
    for (int off = 1; off < 1024; off <<= 1) {
        int v = (tid >= off) ? part[tid - off] : 0;
        __syncthreads();
        part[tid] += v;
        __syncthreads();
    }
    int prev = (tid == 0) ? 0 : part[tid - 1];
    for (int i = 0; i < ITEMS; ++i) {
        int idx = base + i;
        if (idx < N) offsets[idx] = prev + local[i];
    }
    if (tid == blockDim.x - 1) offsets[N] = part[tid];
}

// ---------------------------------------------------------------------------
// 3) fill CSR token lists (attention is permutation-invariant over keys)
// ---------------------------------------------------------------------------
__global__ void fill_kernel(const int* __restrict__ nearest, const int* __restrict__ offsets,
                            int* __restrict__ cursor, int* __restrict__ tokens,
                            int BU, int U, int S) {
    int i = blockIdx.x * blockDim.x + threadIdx.x;
    if (i >= BU) return;
    int b = i / U;
    int u = i - b * U;
    int c = b * S + nearest[i];
    int pos = offsets[c] + atomicAdd(&cursor[c], 1);
    tokens[pos] = u;
}

// ---------------------------------------------------------------------------
// 4) SGEMM  C[M x 128] = A[M x 128] @ W[128 x 128]
//    BM=64 BN=128 BK=16, 256 threads, 4x8 register tile per thread.
//    If fake != nullptr and *ignore_flag, every A row is `fake`.
// ---------------------------------------------------------------------------
#define BM 64
#define BN 128
#define BK 16

__global__ void gemm_kernel(const float* __restrict__ A, const float* __restrict__ W,
                            float* __restrict__ C, int M,
                            const float* __restrict__ fake, const int* __restrict__ ignore_flag) {
    __shared__ float As[BK][BM + 4];   // pad: conflict-light transpose stores
    __shared__ float Bs[BK][BN];
    int tid = threadIdx.x;
    int row0 = blockIdx.x * BM;
    bool ign = (fake != nullptr) && (*ignore_flag != 0);

    int tr = tid & 15;   // row group 0..15 (4 rows each) — varies fastest in wave
    int tc = tid >> 4;   // col group 0..15 (8 cols each) — wave-broadcast B reads

    float acc[4][8];
#pragma unroll
    for (int i = 0; i < 4; ++i)
#pragma unroll
        for (int j = 0; j < 8; ++j) acc[i][j] = 0.f;

    int sr = tid >> 2;            // staging row 0..63
    int sk = (tid & 3) << 2;      // staging k {0,4,8,12}

    for (int k0 = 0; k0 < E_DIM; k0 += BK) {
        const float* asrc = ign ? (fake + k0 + sk)
                                : (A + (size_t)(row0 + sr) * E_DIM + k0 + sk);
        float4 av = *(const float4*)asrc;
        As[sk + 0][sr] = av.x;
        As[sk + 1][sr] = av.y;
        As[sk + 2][sr] = av.z;
        As[sk + 3][sr] = av.w;

        {
            int flat = tid * 4;                    // 1024 of 2048
            int k = flat >> 7, col = flat & 127;
            *(float4*)&Bs[k][col] = *(const float4*)(W + (size_t)(k0 + k) * E_DIM + col);
            flat += 1024;
            k = flat >> 7; col = flat & 127;
            *(float4*)&Bs[k][col] = *(const float4*)(W + (size_t)(k0 + k) * E_DIM + col);
        }
        __syncthreads();

#pragma unroll
        for (int k = 0; k < BK; ++k) {
            float4 a4 = *(const float4*)&As[k][tr * 4];
            float4 b0 = *(const float4*)&Bs[k][tc * 8];
            float4 b1 = *(const float4*)&Bs[k][tc * 8 + 4];
            float af[4] = {a4.x, a4.y, a4.z, a4.w};
            float bf[8] = {b0.x, b0.y, b0.z, b0.w, b1.x, b1.y, b1.z, b1.w};
#pragma unroll
            for (int i = 0; i < 4; ++i)
#pragma unroll
                for (int j = 0; j < 8; ++j) acc[i][j] += af[i] * bf[j];
        }
        __syncthreads();
    }

#pragma unroll
    for (int i = 0; i < 4; ++i) {
        float* dst = C + (size_t)(row0 + tr * 4 + i) * E_DIM + tc * 8;
        *(float4*)dst = *(float4*)&acc[i][0];
        *(float4*)(dst + 4) = *(float4*)&acc[i][4];
    }
}

// ---------------------------------------------------------------------------
// 5) per-cell masked MHA, 1 query, online softmax; one wave per cell.
// ---------------------------------------------------------------------------
__global__ void attn_kernel(const float* __restrict__ Qpre,
                            const float* __restrict__ Koff, const float* __restrict__ Voff,
                            const float* __restrict__ Kon, const float* __restrict__ Von,
                            const int* __restrict__ offsets, const int* __restrict__ tokens,
                            float* __restrict__ AO, int S, int U) {
    int c = blockIdx.x;
    int b = c / S;
    int lane = threadIdx.x;  // 0..63
    float q0 = Qpre[(size_t)(c - b * S) * E_DIM + lane];
    float q1 = Qpre[(size_t)(c - b * S) * E_DIM + 64 + lane];
    float m1 = -INFINITY, l1 = 0.f, o0 = 0.f;
    float m2 = -INFINITY, l2 = 0.f, o1 = 0.f;
    int beg = offsets[c], end = offsets[c + 1];
    const float scale = 0.25f;  // 1/sqrt(dh), dh=16
    for (int t = beg; t <= end; ++t) {
        const float* kr;
        const float* vr;
        if (t < end) {
            int u = tokens[t];
            size_t rr = ((size_t)b * U + u) * E_DIM;
            kr = Koff + rr; vr = Voff + rr;
        } else {
            size_t rr = (size_t)c * E_DIM;
            kr = Kon + rr; vr = Von + rr;
        }
        float k0 = kr[lane], k1 = kr[64 + lane];
        float p0 = q0 * k0, p1 = q1 * k1;
#pragma unroll
        for (int off = 8; off >= 1; off >>= 1) {
            p0 += __shfl_xor(p0, off, 16);
            p1 += __shfl_xor(p1, off, 16);
        }
        float s1 = p0 * scale, s2 = p1 * scale;
        float v0 = vr[lane], v1 = vr[64 + lane];
        float nm = fmaxf(m1, s1);
        float f = __expf(m1 - nm), w = __expf(s1 - nm);
        l1 = l1 * f + w; o0 = o0 * f + w * v0; m1 = nm;
        nm = fmaxf(m2, s2);
        f = __expf(m2 - nm); w = __expf(s2 - nm);
        l2 = l2 * f + w; o1 = o1 * f + w * v1; m2 = nm;
    }
    AO[(size_t)c * E_DIM + lane] = o0 / l1;
    AO[(size_t)c * E_DIM + 64 + lane] = o1 / l2;
}

// ---------------------------------------------------------------------------
extern "C" void kernel_launch(void* const* d_in, const int* in_sizes, int n_in,
                              void* d_out, int out_size, void* d_ws, size_t ws_size,
                              hipStream_t stream) {
    const float* xc_off  = (const float*)d_in[0];
    const float* xc_on   = (const float*)d_in[1];
    const float* zc_off  = (const float*)d_in[2];
    const float* zc_on   = (const float*)d_in[3];
    const float* latents = (const float*)d_in[4];
    const float* fake    = (const float*)d_in[5];
    const float* Wq      = (const float*)d_in[6];
    const float* Wk      = (const float*)d_in[7];
    const float* Wv      = (const float*)d_in[8];
    const float* Wo      = (const float*)d_in[9];
    const int*   ignore  = (const int*)d_in[10];

    const int E = in_sizes[5];              // 128
    const int S = in_sizes[4] / E;          // 4096
    const int B = in_sizes[1] / (S * 2);    // 4
    const int U = in_sizes[0] / (B * 2);    // 4096
    const int BS = B * S, BU = B * U;

    char* ws = (char*)d_ws;
    size_t off = 0;
    auto alloc = [&](size_t bytes) {
        size_t r = off;
        off += (bytes + 255) & ~(size_t)255;
        return r;
    };
    int*   nearest = (int*)(ws + alloc((size_t)BU * 4));
    int*   counts  = (int*)(ws + alloc((size_t)BS * 4));
    int*   cursor  = (int*)(ws + alloc((size_t)BS * 4));
    int*   offsets = (int*)(ws + alloc((size_t)(BS + 1) * 4));
    int*   tokens  = (int*)(ws + alloc((size_t)BU * 4));
    float* Qpre    = (float*)(ws + alloc((size_t)S * E * 4));
    float* Koff    = (float*)(ws + alloc((size_t)BU * E * 4));
    float* Voff    = (float*)(ws + alloc((size_t)BU * E * 4));
    float* Kon     = (float*)(ws + alloc((size_t)BS * E * 4));
    float* Von     = (float*)(ws + alloc((size_t)BS * E * 4));
    float* AO      = (float*)(ws + alloc((size_t)BS * E * 4));

    hipMemsetAsync(counts, 0, (size_t)BS * 4, stream);
    hipMemsetAsync(cursor, 0, (size_t)BS * 4, stream);

    dim3 ngrid(U / 64, B);
    nearest_kernel<<<ngrid, 256, 0, stream>>>(xc_off, xc_on, nearest, counts, U, S);
    scan_kernel<<<1, 1024, 0, stream>>>(counts, offsets, BS);
    fill_kernel<<<(BU + 255) / 256, 256, 0, stream>>>(nearest, offsets, cursor, tokens, BU, U, S);

    gemm_kernel<<<S / BM, 256, 0, stream>>>(latents, Wq, Qpre, S, nullptr, nullptr);
    gemm_kernel<<<BU / BM, 256, 0, stream>>>(zc_off, Wk, Koff, BU, nullptr, nullptr);
    gemm_kernel<<<BU / BM, 256, 0, stream>>>(zc_off, Wv, Voff, BU, nullptr, nullptr);
    gemm_kernel<<<BS / BM, 256, 0, stream>>>(zc_on, Wk, Kon, BS, fake, ignore);
    gemm_kernel<<<BS / BM, 256, 0, stream>>>(zc_on, Wv, Von, BS, fake, ignore);

    attn_kernel<<<BS, 64, 0, stream>>>(Qpre, Koff, Voff, Kon, Von, offsets, tokens, AO, S, U);

    gemm_kernel<<<BS / BM, 256, 0, stream>>>(AO, Wo, (float*)d_out, BS, nullptr, nullptr);
}

// Round 3
// 215.063 us; speedup vs baseline: 9.5611x; 1.3068x over previous
//
#include <hip/hip_runtime.h>
#include <math.h>
#include <float.h>

#define E_DIM 128

__device__ inline void lexmin(float& d, int& i, float d2, int i2) {
    if (d2 < d || (d2 == d && i2 < i)) { d = d2; i = i2; }
}

// ---------------------------------------------------------------------------
// 1) nearest grid cell per off-grid point (L1 argmin, first-min tie-break).
//    512 blocks: 32 u's per block, 16 S-partitions x 16 u-groups (2 u/thread).
//    float4 LDS reads (2 cells), 4 independent min chains per thread.
// ---------------------------------------------------------------------------
__global__ void nearest_kernel(const float* __restrict__ xc_off, const float* __restrict__ xc_on,
                               int* __restrict__ nearest, int* __restrict__ counts, int U, int S) {
    __shared__ float4 on[2048];          // 4096 cells (32 KB)
    __shared__ float sh_d[16][32];
    __shared__ int   sh_i[16][32];
    int b = blockIdx.y;
    const float4* onb = (const float4*)(xc_on + (size_t)b * S * 2);
    for (int i = threadIdx.x; i < S / 2; i += blockDim.x) on[i] = onb[i];
    __syncthreads();
    int part = threadIdx.x >> 4;         // 0..15 (S-partition)
    int ug   = threadIdx.x & 15;         // 0..15 (u-group)
    int u0 = blockIdx.x * 32 + ug * 2;
    const float2* offb = (const float2*)(xc_off + (size_t)b * U * 2);
    float2 pA = offb[u0], pB = offb[u0 + 1];
    int h0 = part * (S / 32);            // 128 float4 per partition (=256 cells)
    int h1 = h0 + (S / 32);
    float dA0 = FLT_MAX, dA1 = FLT_MAX, dB0 = FLT_MAX, dB1 = FLT_MAX;
    int iA0 = 0, iA1 = 0, iB0 = 0, iB1 = 0;
    for (int h = h0; h < h1; ++h) {
        float4 cc = on[h];
        int s = h * 2;
        float a0 = fabsf(pA.x - cc.x) + fabsf(pA.y - cc.y);
        float a1 = fabsf(pA.x - cc.z) + fabsf(pA.y - cc.w);
        float b0 = fabsf(pB.x - cc.x) + fabsf(pB.y - cc.y);
        float b1 = fabsf(pB.x - cc.z) + fabsf(pB.y - cc.w);
        if (a0 < dA0) { dA0 = a0; iA0 = s; }
        if (a1 < dA1) { dA1 = a1; iA1 = s + 1; }
        if (b0 < dB0) { dB0 = b0; iB0 = s; }
        if (b1 < dB1) { dB1 = b1; iB1 = s + 1; }
    }
    lexmin(dA0, iA0, dA1, iA1);          // lexicographic => first-min semantics
    lexmin(dB0, iB0, dB1, iB1);
    sh_d[part][ug * 2] = dA0;     sh_i[part][ug * 2] = iA0;
    sh_d[part][ug * 2 + 1] = dB0; sh_i[part][ug * 2 + 1] = iB0;
    __syncthreads();
    if (threadIdx.x < 32) {
        int ul = threadIdx.x;
        float d = sh_d[0][ul]; int i = sh_i[0][ul];
#pragma unroll
        for (int p = 1; p < 16; ++p) lexmin(d, i, sh_d[p][ul], sh_i[p][ul]);
        int u = blockIdx.x * 32 + ul;
        nearest[b * U + u] = i;
        atomicAdd(&counts[b * S + i], 1);
    }
}

// ---------------------------------------------------------------------------
// 2) exclusive scan of counts -> CSR offsets (single block, N <= 16384)
// ---------------------------------------------------------------------------
__global__ void scan_kernel(const int* __restrict__ counts, int* __restrict__ offsets, int N) {
    __shared__ int part[1024];
    const int ITEMS = 16;
    int tid = threadIdx.x;
    int base = tid * ITEMS;
    int local[ITEMS];
    int sum = 0;
    for (int i = 0; i < ITEMS; ++i) {
        int idx = base + i;
        int v = (idx < N) ? counts[idx] : 0;
        local[i] = sum;
        sum += v;
    }
    part[tid] = sum;
    __syncthreads();
    for (int off = 1; off < 1024; off <<= 1) {
        int v = (tid >= off) ? part[tid - off] : 0;
        __syncthreads();
        part[tid] += v;
        __syncthreads();
    }
    int prev = (tid == 0) ? 0 : part[tid - 1];
    for (int i = 0; i < ITEMS; ++i) {
        int idx = base + i;
        if (idx < N) offsets[idx] = prev + local[i];
    }
    if (tid == blockDim.x - 1) offsets[N] = part[tid];
}

// ---------------------------------------------------------------------------
// 3) fill CSR token lists (attention is permutation-invariant over keys)
// ---------------------------------------------------------------------------
__global__ void fill_kernel(const int* __restrict__ nearest, const int* __restrict__ offsets,
                            int* __restrict__ cursor, int* __restrict__ tokens,
                            int BU, int U, int S) {
    int i = blockIdx.x * blockDim.x + threadIdx.x;
    if (i >= BU) return;
    int b = i / U;
    int u = i - b * U;
    int c = b * S + nearest[i];
    int pos = offsets[c] + atomicAdd(&cursor[c], 1);
    tokens[pos] = u;
}

// ---------------------------------------------------------------------------
// 4) SGEMM  C[M x 128] = A[M x 128] @ W[128 x 128]
//    BM=64 BN=128 BK=16, 256 threads, 4x8 register tile per thread.
// ---------------------------------------------------------------------------
#define BM 64
#define BN 128
#define BK 16

__global__ void gemm_kernel(const float* __restrict__ A, const float* __restrict__ W,
                            float* __restrict__ C, int M) {
    __shared__ float As[BK][BM + 4];
    __shared__ float Bs[BK][BN];
    int tid = threadIdx.x;
    int row0 = blockIdx.x * BM;

    int tr = tid & 15;
    int tc = tid >> 4;

    float acc[4][8];
#pragma unroll
    for (int i = 0; i < 4; ++i)
#pragma unroll
        for (int j = 0; j < 8; ++j) acc[i][j] = 0.f;

    int sr = tid >> 2;
    int sk = (tid & 3) << 2;

    for (int k0 = 0; k0 < E_DIM; k0 += BK) {
        float4 av = *(const float4*)(A + (size_t)(row0 + sr) * E_DIM + k0 + sk);
        As[sk + 0][sr] = av.x;
        As[sk + 1][sr] = av.y;
        As[sk + 2][sr] = av.z;
        As[sk + 3][sr] = av.w;
        {
            int flat = tid * 4;
            int k = flat >> 7, col = flat & 127;
            *(float4*)&Bs[k][col] = *(const float4*)(W + (size_t)(k0 + k) * E_DIM + col);
            flat += 1024;
            k = flat >> 7; col = flat & 127;
            *(float4*)&Bs[k][col] = *(const float4*)(W + (size_t)(k0 + k) * E_DIM + col);
        }
        __syncthreads();
#pragma unroll
        for (int k = 0; k < BK; ++k) {
            float4 a4 = *(const float4*)&As[k][tr * 4];
            float4 b0 = *(const float4*)&Bs[k][tc * 8];
            float4 b1 = *(const float4*)&Bs[k][tc * 8 + 4];
            float af[4] = {a4.x, a4.y, a4.z, a4.w};
            float bf[8] = {b0.x, b0.y, b0.z, b0.w, b1.x, b1.y, b1.z, b1.w};
#pragma unroll
            for (int i = 0; i < 4; ++i)
#pragma unroll
                for (int j = 0; j < 8; ++j) acc[i][j] += af[i] * bf[j];
        }
        __syncthreads();
    }
#pragma unroll
    for (int i = 0; i < 4; ++i) {
        float* dst = C + (size_t)(row0 + tr * 4 + i) * E_DIM + tc * 8;
        *(float4*)dst = *(float4*)&acc[i][0];
        *(float4*)(dst + 4) = *(float4*)&acc[i][4];
    }
}

// Dual-weight SGEMM: C0 = A@W0, C1 = A@W1 (A staged once).
// If fake != nullptr and *ignore_flag, every A row is `fake`.
__global__ void gemm2_kernel(const float* __restrict__ A,
                             const float* __restrict__ W0, const float* __restrict__ W1,
                             float* __restrict__ C0, float* __restrict__ C1, int M,
                             const float* __restrict__ fake, const int* __restrict__ ignore_flag) {
    __shared__ float As[BK][BM + 4];
    __shared__ float Bs0[BK][BN];
    __shared__ float Bs1[BK][BN];
    int tid = threadIdx.x;
    int row0 = blockIdx.x * BM;
    bool ign = (fake != nullptr) && (*ignore_flag != 0);

    int tr = tid & 15;
    int tc = tid >> 4;

    float acc0[4][8], acc1[4][8];
#pragma unroll
    for (int i = 0; i < 4; ++i)
#pragma unroll
        for (int j = 0; j < 8; ++j) { acc0[i][j] = 0.f; acc1[i][j] = 0.f; }

    int sr = tid >> 2;
    int sk = (tid & 3) << 2;

    for (int k0 = 0; k0 < E_DIM; k0 += BK) {
        const float* asrc = ign ? (fake + k0 + sk)
                                : (A + (size_t)(row0 + sr) * E_DIM + k0 + sk);
        float4 av = *(const float4*)asrc;
        As[sk + 0][sr] = av.x;
        As[sk + 1][sr] = av.y;
        As[sk + 2][sr] = av.z;
        As[sk + 3][sr] = av.w;
        {
            int flat = tid * 4;
            int k = flat >> 7, col = flat & 127;
            *(float4*)&Bs0[k][col] = *(const float4*)(W0 + (size_t)(k0 + k) * E_DIM + col);
            *(float4*)&Bs1[k][col] = *(const float4*)(W1 + (size_t)(k0 + k) * E_DIM + col);
            flat += 1024;
            k = flat >> 7; col = flat & 127;
            *(float4*)&Bs0[k][col] = *(const float4*)(W0 + (size_t)(k0 + k) * E_DIM + col);
            *(float4*)&Bs1[k][col] = *(const float4*)(W1 + (size_t)(k0 + k) * E_DIM + col);
        }
        __syncthreads();
#pragma unroll
        for (int k = 0; k < BK; ++k) {
            float4 a4 = *(const float4*)&As[k][tr * 4];
            float af[4] = {a4.x, a4.y, a4.z, a4.w};
            float4 b0 = *(const float4*)&Bs0[k][tc * 8];
            float4 b1 = *(const float4*)&Bs0[k][tc * 8 + 4];
            float bf[8] = {b0.x, b0.y, b0.z, b0.w, b1.x, b1.y, b1.z, b1.w};
#pragma unroll
            for (int i = 0; i < 4; ++i)
#pragma unroll
                for (int j = 0; j < 8; ++j) acc0[i][j] += af[i] * bf[j];
            float4 c0 = *(const float4*)&Bs1[k][tc * 8];
            float4 c1 = *(const float4*)&Bs1[k][tc * 8 + 4];
            float cf[8] = {c0.x, c0.y, c0.z, c0.w, c1.x, c1.y, c1.z, c1.w};
#pragma unroll
            for (int i = 0; i < 4; ++i)
#pragma unroll
                for (int j = 0; j < 8; ++j) acc1[i][j] += af[i] * cf[j];
        }
        __syncthreads();
    }
#pragma unroll
    for (int i = 0; i < 4; ++i) {
        float* d0 = C0 + (size_t)(row0 + tr * 4 + i) * E_DIM + tc * 8;
        *(float4*)d0 = *(float4*)&acc0[i][0];
        *(float4*)(d0 + 4) = *(float4*)&acc0[i][4];
        float* d1 = C1 + (size_t)(row0 + tr * 4 + i) * E_DIM + tc * 8;
        *(float4*)d1 = *(float4*)&acc1[i][0];
        *(float4*)(d1 + 4) = *(float4*)&acc1[i][4];
    }
}

// ---------------------------------------------------------------------------
// 5) per-cell masked MHA, 1 query, online softmax; one wave per cell.
// ---------------------------------------------------------------------------
__global__ void attn_kernel(const float* __restrict__ Qpre,
                            const float* __restrict__ Koff, const float* __restrict__ Voff,
                            const float* __restrict__ Kon, const float* __restrict__ Von,
                            const int* __restrict__ offsets, const int* __restrict__ tokens,
                            float* __restrict__ AO, int S, int U) {
    int c = blockIdx.x;
    int b = c / S;
    int lane = threadIdx.x;  // 0..63
    float q0 = Qpre[(size_t)(c - b * S) * E_DIM + lane];
    float q1 = Qpre[(size_t)(c - b * S) * E_DIM + 64 + lane];
    float m1 = -INFINITY, l1 = 0.f, o0 = 0.f;
    float m2 = -INFINITY, l2 = 0.f, o1 = 0.f;
    int beg = offsets[c], end = offsets[c + 1];
    const float scale = 0.25f;  // 1/sqrt(dh), dh=16
    for (int t = beg; t <= end; ++t) {
        const float* kr;
        const float* vr;
        if (t < end) {
            int u = tokens[t];
            size_t rr = ((size_t)b * U + u) * E_DIM;
            kr = Koff + rr; vr = Voff + rr;
        } else {
            size_t rr = (size_t)c * E_DIM;
            kr = Kon + rr; vr = Von + rr;
        }
        float k0 = kr[lane], k1 = kr[64 + lane];
        float p0 = q0 * k0, p1 = q1 * k1;
#pragma unroll
        for (int off = 8; off >= 1; off >>= 1) {
            p0 += __shfl_xor(p0, off, 16);
            p1 += __shfl_xor(p1, off, 16);
        }
        float s1 = p0 * scale, s2 = p1 * scale;
        float v0 = vr[lane], v1 = vr[64 + lane];
        float nm = fmaxf(m1, s1);
        float f = __expf(m1 - nm), w = __expf(s1 - nm);
        l1 = l1 * f + w; o0 = o0 * f + w * v0; m1 = nm;
        nm = fmaxf(m2, s2);
        f = __expf(m2 - nm); w = __expf(s2 - nm);
        l2 = l2 * f + w; o1 = o1 * f + w * v1; m2 = nm;
    }
    AO[(size_t)c * E_DIM + lane] = o0 / l1;
    AO[(size_t)c * E_DIM + 64 + lane] = o1 / l2;
}

// ---------------------------------------------------------------------------
extern "C" void kernel_launch(void* const* d_in, const int* in_sizes, int n_in,
                              void* d_out, int out_size, void* d_ws, size_t ws_size,
                              hipStream_t stream) {
    const float* xc_off  = (const float*)d_in[0];
    const float* xc_on   = (const float*)d_in[1];
    const float* zc_off  = (const float*)d_in[2];
    const float* zc_on   = (const float*)d_in[3];
    const float* latents = (const float*)d_in[4];
    const float* fake    = (const float*)d_in[5];
    const float* Wq      = (const float*)d_in[6];
    const float* Wk      = (const float*)d_in[7];
    const float* Wv      = (const float*)d_in[8];
    const float* Wo      = (const float*)d_in[9];
    const int*   ignore  = (const int*)d_in[10];

    const int E = in_sizes[5];              // 128
    const int S = in_sizes[4] / E;          // 4096
    const int B = in_sizes[1] / (S * 2);    // 4
    const int U = in_sizes[0] / (B * 2);    // 4096
    const int BS = B * S, BU = B * U;

    char* ws = (char*)d_ws;
    size_t off = 0;
    auto alloc = [&](size_t bytes) {
        size_t r = off;
        off += (bytes + 255) & ~(size_t)255;
        return r;
    };
    int*   nearest = (int*)(ws + alloc((size_t)BU * 4));
    int*   counts  = (int*)(ws + alloc((size_t)BS * 4));
    int*   cursor  = (int*)(ws + alloc((size_t)BS * 4));
    int*   offsets = (int*)(ws + alloc((size_t)(BS + 1) * 4));
    int*   tokens  = (int*)(ws + alloc((size_t)BU * 4));
    float* Qpre    = (float*)(ws + alloc((size_t)S * E * 4));
    float* Koff    = (float*)(ws + alloc((size_t)BU * E * 4));
    float* Voff    = (float*)(ws + alloc((size_t)BU * E * 4));
    float* Kon     = (float*)(ws + alloc((size_t)BS * E * 4));
    float* Von     = (float*)(ws + alloc((size_t)BS * E * 4));
    float* AO      = (float*)(ws + alloc((size_t)BS * E * 4));

    hipMemsetAsync(counts, 0, (size_t)BS * 4, stream);
    hipMemsetAsync(cursor, 0, (size_t)BS * 4, stream);

    dim3 ngrid(U / 32, B);
    nearest_kernel<<<ngrid, 256, 0, stream>>>(xc_off, xc_on, nearest, counts, U, S);
    scan_kernel<<<1, 1024, 0, stream>>>(counts, offsets, BS);
    fill_kernel<<<(BU + 255) / 256, 256, 0, stream>>>(nearest, offsets, cursor, tokens, BU, U, S);

    gemm_kernel<<<S / BM, 256, 0, stream>>>(latents, Wq, Qpre, S);
    gemm2_kernel<<<BU / BM, 256, 0, stream>>>(zc_off, Wk, Wv, Koff, Voff, BU, nullptr, nullptr);
    gemm2_kernel<<<BS / BM, 256, 0, stream>>>(zc_on, Wk, Wv, Kon, Von, BS, fake, ignore);

    attn_kernel<<<BS, 64, 0, stream>>>(Qpre, Koff, Voff, Kon, Von, offsets, tokens, AO, S, U);

    gemm_kernel<<<BS / BM, 256, 0, stream>>>(AO, Wo, (float*)d_out, BS);
}

// Round 4
// 175.487 us; speedup vs baseline: 11.7173x; 1.2255x over previous
//
#include <hip/hip_runtime.h>
#include <math.h>
#include <float.h>

#define E_DIM 128

typedef __bf16 bf16x8 __attribute__((ext_vector_type(8)));
typedef float  f32x4  __attribute__((ext_vector_type(4)));

__device__ inline unsigned short f2bf(float f) {
    union { float f; unsigned int u; } x; x.f = f;
    unsigned int r = x.u + 0x7fffu + ((x.u >> 16) & 1u);   // round-to-nearest-even
    return (unsigned short)(r >> 16);
}

__device__ inline void lexmin(float& d, int& i, float d2, int i2) {
    if (d2 < d || (d2 == d && i2 < i)) { d = d2; i = i2; }
}

// ---------------------------------------------------------------------------
// 0) transpose weights to bf16 n-major: Wt[n][k] = bf16(W[k][n]), for 4 weights
// ---------------------------------------------------------------------------
__global__ void prep_wt_kernel(const float* __restrict__ Wq, const float* __restrict__ Wk,
                               const float* __restrict__ Wv, const float* __restrict__ Wo,
                               unsigned short* __restrict__ WqT, unsigned short* __restrict__ WkT,
                               unsigned short* __restrict__ WvT, unsigned short* __restrict__ WoT) {
    int idx = blockIdx.x * blockDim.x + threadIdx.x;   // 0..65535
    int w = idx >> 14;
    int rem = idx & 16383;
    int k = rem >> 7;
    int n = rem & 127;
    const float* src = (w == 0) ? Wq : (w == 1) ? Wk : (w == 2) ? Wv : Wo;
    unsigned short* dst = (w == 0) ? WqT : (w == 1) ? WkT : (w == 2) ? WvT : WoT;
    dst[n * E_DIM + k] = f2bf(src[k * E_DIM + n]);
}

// ---------------------------------------------------------------------------
// 1) nearest grid cell per off-grid point (L1 argmin, first-min tie-break).
// ---------------------------------------------------------------------------
__global__ void nearest_kernel(const float* __restrict__ xc_off, const float* __restrict__ xc_on,
                               int* __restrict__ nearest, int* __restrict__ counts, int U, int S) {
    __shared__ float4 on[2048];          // 4096 cells (32 KB)
    __shared__ float sh_d[16][32];
    __shared__ int   sh_i[16][32];
    int b = blockIdx.y;
    const float4* onb = (const float4*)(xc_on + (size_t)b * S * 2);
    for (int i = threadIdx.x; i < S / 2; i += blockDim.x) on[i] = onb[i];
    __syncthreads();
    int part = threadIdx.x >> 4;         // 0..15 (S-partition)
    int ug   = threadIdx.x & 15;         // 0..15 (u-group)
    int u0 = blockIdx.x * 32 + ug * 2;
    const float2* offb = (const float2*)(xc_off + (size_t)b * U * 2);
    float2 pA = offb[u0], pB = offb[u0 + 1];
    int h0 = part * (S / 32);
    int h1 = h0 + (S / 32);
    float dA0 = FLT_MAX, dA1 = FLT_MAX, dB0 = FLT_MAX, dB1 = FLT_MAX;
    int iA0 = 0, iA1 = 0, iB0 = 0, iB1 = 0;
    for (int h = h0; h < h1; ++h) {
        float4 cc = on[h];
        int s = h * 2;
        float a0 = fabsf(pA.x - cc.x) + fabsf(pA.y - cc.y);
        float a1 = fabsf(pA.x - cc.z) + fabsf(pA.y - cc.w);
        float b0 = fabsf(pB.x - cc.x) + fabsf(pB.y - cc.y);
        float b1 = fabsf(pB.x - cc.z) + fabsf(pB.y - cc.w);
        if (a0 < dA0) { dA0 = a0; iA0 = s; }
        if (a1 < dA1) { dA1 = a1; iA1 = s + 1; }
        if (b0 < dB0) { dB0 = b0; iB0 = s; }
        if (b1 < dB1) { dB1 = b1; iB1 = s + 1; }
    }
    lexmin(dA0, iA0, dA1, iA1);
    lexmin(dB0, iB0, dB1, iB1);
    sh_d[part][ug * 2] = dA0;     sh_i[part][ug * 2] = iA0;
    sh_d[part][ug * 2 + 1] = dB0; sh_i[part][ug * 2 + 1] = iB0;
    __syncthreads();
    if (threadIdx.x < 32) {
        int ul = threadIdx.x;
        float d = sh_d[0][ul]; int i = sh_i[0][ul];
#pragma unroll
        for (int p = 1; p < 16; ++p) lexmin(d, i, sh_d[p][ul], sh_i[p][ul]);
        int u = blockIdx.x * 32 + ul;
        nearest[b * U + u] = i;
        atomicAdd(&counts[b * S + i], 1);
    }
}

// ---------------------------------------------------------------------------
// 2) exclusive scan of counts -> CSR offsets (single block, N <= 16384)
// ---------------------------------------------------------------------------
__global__ void scan_kernel(const int* __restrict__ counts, int* __restrict__ offsets, int N) {
    __shared__ int part[1024];
    const int ITEMS = 16;
    int tid = threadIdx.x;
    int base = tid * ITEMS;
    int local[ITEMS];
    int sum = 0;
    for (int i = 0; i < ITEMS; ++i) {
        int idx = base + i;
        int v = (idx < N) ? counts[idx] : 0;
        local[i] = sum;
        sum += v;
    }
    part[tid] = sum;
    __syncthreads();
    for (int off = 1; off < 1024; off <<= 1) {
        int v = (tid >= off) ? part[tid - off] : 0;
        __syncthreads();
        part[tid] += v;
        __syncthreads();
    }
    int prev = (tid == 0) ? 0 : part[tid - 1];
    for (int i = 0; i < ITEMS; ++i) {
        int idx = base + i;
        if (idx < N) offsets[idx] = prev + local[i];
    }
    if (tid == blockDim.x - 1) offsets[N] = part[tid];
}

// ---------------------------------------------------------------------------
// 3) fill CSR token lists (attention is permutation-invariant over keys)
// ---------------------------------------------------------------------------
__global__ void fill_kernel(const int* __restrict__ nearest, const int* __restrict__ offsets,
                            int* __restrict__ cursor, int* __restrict__ tokens,
                            int BU, int U, int S) {
    int i = blockIdx.x * blockDim.x + threadIdx.x;
    if (i >= BU) return;
    int b = i / U;
    int u = i - b * U;
    int c = b * S + nearest[i];
    int pos = offsets[c] + atomicAdd(&cursor[c], 1);
    tokens[pos] = u;
}

// ---------------------------------------------------------------------------
// 4) MFMA bf16 GEMM: C[M x 128] = A[M x 128] @ W[128 x 128], K=128 one pass.
//    Wt is bf16 n-major (Wt[n][k]). BM=64, 128 threads (2 waves), each wave
//    computes 32 rows: 2 m-frags x 8 n-frags of 16x16x32 MFMAs.
//    LDS XOR-swizzle (byte ^= (row&7)<<4) keeps ds_read_b128 conflict-light.
//    If fake != nullptr and *ignore_flag: every A row is `fake`.
// ---------------------------------------------------------------------------
__global__ __launch_bounds__(128) void gemm_mfma_kernel(
        const float* __restrict__ A, const unsigned short* __restrict__ Wt,
        float* __restrict__ C, int M,
        const float* __restrict__ fake, const int* __restrict__ ignore_flag) {
    __shared__ unsigned short Asm[64 * E_DIM];    // 16 KB, swizzled
    __shared__ unsigned short Wsm[E_DIM * E_DIM]; // 32 KB, swizzled
    const int tid = threadIdx.x;
    const int lane = tid & 63;
    const int wv = tid >> 6;                      // 0..1
    const int row0 = blockIdx.x * 64;
    const bool ign = (fake != nullptr) && (*ignore_flag != 0);

    // ---- stage A: wave wv covers rows [wv*32, wv*32+32) = contiguous 16 KB ----
    {
        const float* abase = A + (size_t)(row0 + wv * 32) * E_DIM;
#pragma unroll
        for (int i = 0; i < 16; ++i) {
            int e = (lane + i * 64) * 4;          // elem offset in 32x128 chunk
            int r = wv * 32 + (e >> 7);
            int c = e & 127;
            float4 v = *(const float4*)(ign ? (fake + c) : (abase + e));
            unsigned int lo = (unsigned int)f2bf(v.x) | ((unsigned int)f2bf(v.y) << 16);
            unsigned int hi = (unsigned int)f2bf(v.z) | ((unsigned int)f2bf(v.w) << 16);
            int byte = (c * 2) ^ ((r & 7) << 4);
            *(uint2*)((char*)Asm + r * 256 + byte) = make_uint2(lo, hi);
        }
        // ---- stage Wt: 32 KB bf16, 16-B chunks, swizzled ----
#pragma unroll
        for (int i = 0; i < 16; ++i) {
            int gb = (wv * 1024 + i * 64 + lane) * 16;   // global byte
            int n = gb >> 8;
            int cb = gb & 255;
            uint4 v = *(const uint4*)((const char*)Wt + gb);
            *(uint4*)((char*)Wsm + n * 256 + (cb ^ ((n & 7) << 4))) = v;
        }
    }
    __syncthreads();

    const int l15 = lane & 15;
    const int kg = lane >> 4;                     // 0..3
    f32x4 zz = {0.f, 0.f, 0.f, 0.f};
    f32x4 acc[2][8];
#pragma unroll
    for (int mi = 0; mi < 2; ++mi)
#pragma unroll
        for (int nf = 0; nf < 8; ++nf) acc[mi][nf] = zz;

#pragma unroll
    for (int kc = 0; kc < 4; ++kc) {
        int kb = (kc * 32 + kg * 8) * 2;          // k byte offset (16 B chunk)
        int r0 = wv * 32 + l15;
        int r1 = r0 + 16;
        bf16x8 a0 = *(const bf16x8*)((char*)Asm + r0 * 256 + (kb ^ ((r0 & 7) << 4)));
        bf16x8 a1 = *(const bf16x8*)((char*)Asm + r1 * 256 + (kb ^ ((r1 & 7) << 4)));
#pragma unroll
        for (int nf = 0; nf < 8; ++nf) {
            int n = nf * 16 + l15;
            bf16x8 b = *(const bf16x8*)((char*)Wsm + n * 256 + (kb ^ ((n & 7) << 4)));
            acc[0][nf] = __builtin_amdgcn_mfma_f32_16x16x32_bf16(a0, b, acc[0][nf], 0, 0, 0);
            acc[1][nf] = __builtin_amdgcn_mfma_f32_16x16x32_bf16(a1, b, acc[1][nf], 0, 0, 0);
        }
    }

    // ---- epilogue: C[row=(l>>4)*4+r][col=l&15] per fragment ----
    const int orow = kg * 4;
#pragma unroll
    for (int mi = 0; mi < 2; ++mi) {
        int rbase = row0 + wv * 32 + mi * 16 + orow;
#pragma unroll
        for (int r = 0; r < 4; ++r) {
            float* dst = C + (size_t)(rbase + r) * E_DIM + l15;
#pragma unroll
            for (int nf = 0; nf < 8; ++nf) dst[nf * 16] = acc[mi][nf][r];
        }
    }
}

// ---------------------------------------------------------------------------
// 5) per-cell masked MHA, 1 query, online softmax; one wave per cell.
// ---------------------------------------------------------------------------
__global__ void attn_kernel(const float* __restrict__ Qpre,
                            const float* __restrict__ Koff, const float* __restrict__ Voff,
                            const float* __restrict__ Kon, const float* __restrict__ Von,
                            const int* __restrict__ offsets, const int* __restrict__ tokens,
                            float* __restrict__ AO, int S, int U) {
    int c = blockIdx.x;
    int b = c / S;
    int lane = threadIdx.x;  // 0..63
    float q0 = Qpre[(size_t)(c - b * S) * E_DIM + lane];
    float q1 = Qpre[(size_t)(c - b * S) * E_DIM + 64 + lane];
    float m1 = -INFINITY, l1 = 0.f, o0 = 0.f;
    float m2 = -INFINITY, l2 = 0.f, o1 = 0.f;
    int beg = offsets[c], end = offsets[c + 1];
    const float scale = 0.25f;  // 1/sqrt(dh), dh=16
    for (int t = beg; t <= end; ++t) {
        const float* kr;
        const float* vr;
        if (t < end) {
            int u = tokens[t];
            size_t rr = ((size_t)b * U + u) * E_DIM;
            kr = Koff + rr; vr = Voff + rr;
        } else {
            size_t rr = (size_t)c * E_DIM;
            kr = Kon + rr; vr = Von + rr;
        }
        float k0 = kr[lane], k1 = kr[64 + lane];
        float p0 = q0 * k0, p1 = q1 * k1;
#pragma unroll
        for (int off = 8; off >= 1; off >>= 1) {
            p0 += __shfl_xor(p0, off, 16);
            p1 += __shfl_xor(p1, off, 16);
        }
        float s1 = p0 * scale, s2 = p1 * scale;
        float v0 = vr[lane], v1 = vr[64 + lane];
        float nm = fmaxf(m1, s1);
        float f = __expf(m1 - nm), w = __expf(s1 - nm);
        l1 = l1 * f + w; o0 = o0 * f + w * v0; m1 = nm;
        nm = fmaxf(m2, s2);
        f = __expf(m2 - nm); w = __expf(s2 - nm);
        l2 = l2 * f + w; o1 = o1 * f + w * v1; m2 = nm;
    }
    AO[(size_t)c * E_DIM + lane] = o0 / l1;
    AO[(size_t)c * E_DIM + 64 + lane] = o1 / l2;
}

// ---------------------------------------------------------------------------
extern "C" void kernel_launch(void* const* d_in, const int* in_sizes, int n_in,
                              void* d_out, int out_size, void* d_ws, size_t ws_size,
                              hipStream_t stream) {
    const float* xc_off  = (const float*)d_in[0];
    const float* xc_on   = (const float*)d_in[1];
    const float* zc_off  = (const float*)d_in[2];
    const float* zc_on   = (const float*)d_in[3];
    const float* latents = (const float*)d_in[4];
    const float* fake    = (const float*)d_in[5];
    const float* Wq      = (const float*)d_in[6];
    const float* Wk      = (const float*)d_in[7];
    const float* Wv      = (const float*)d_in[8];
    const float* Wo      = (const float*)d_in[9];
    const int*   ignore  = (const int*)d_in[10];

    const int E = in_sizes[5];              // 128
    const int S = in_sizes[4] / E;          // 4096
    const int B = in_sizes[1] / (S * 2);    // 4
    const int U = in_sizes[0] / (B * 2);    // 4096
    const int BS = B * S, BU = B * U;

    char* ws = (char*)d_ws;
    size_t off = 0;
    auto alloc = [&](size_t bytes) {
        size_t r = off;
        off += (bytes + 255) & ~(size_t)255;
        return r;
    };
    int*   nearest = (int*)(ws + alloc((size_t)BU * 4));
    int*   counts  = (int*)(ws + alloc((size_t)BS * 4));
    int*   cursor  = (int*)(ws + alloc((size_t)BS * 4));
    int*   offsets = (int*)(ws + alloc((size_t)(BS + 1) * 4));
    int*   tokens  = (int*)(ws + alloc((size_t)BU * 4));
    float* Qpre    = (float*)(ws + alloc((size_t)S * E * 4));
    float* Koff    = (float*)(ws + alloc((size_t)BU * E * 4));
    float* Voff    = (float*)(ws + alloc((size_t)BU * E * 4));
    float* Kon     = (float*)(ws + alloc((size_t)BS * E * 4));
    float* Von     = (float*)(ws + alloc((size_t)BS * E * 4));
    float* AO      = (float*)(ws + alloc((size_t)BS * E * 4));
    unsigned short* WqT = (unsigned short*)(ws + alloc((size_t)E * E * 2));
    unsigned short* WkT = (unsigned short*)(ws + alloc((size_t)E * E * 2));
    unsigned short* WvT = (unsigned short*)(ws + alloc((size_t)E * E * 2));
    unsigned short* WoT = (unsigned short*)(ws + alloc((size_t)E * E * 2));

    hipMemsetAsync(counts, 0, (size_t)BS * 4, stream);
    hipMemsetAsync(cursor, 0, (size_t)BS * 4, stream);

    prep_wt_kernel<<<(4 * E * E) / 256, 256, 0, stream>>>(Wq, Wk, Wv, Wo, WqT, WkT, WvT, WoT);

    dim3 ngrid(U / 32, B);
    nearest_kernel<<<ngrid, 256, 0, stream>>>(xc_off, xc_on, nearest, counts, U, S);
    scan_kernel<<<1, 1024, 0, stream>>>(counts, offsets, BS);
    fill_kernel<<<(BU + 255) / 256, 256, 0, stream>>>(nearest, offsets, cursor, tokens, BU, U, S);

    gemm_mfma_kernel<<<S / 64, 128, 0, stream>>>(latents, WqT, Qpre, S, nullptr, nullptr);
    gemm_mfma_kernel<<<BU / 64, 128, 0, stream>>>(zc_off, WkT, Koff, BU, nullptr, nullptr);
    gemm_mfma_kernel<<<BU / 64, 128, 0, stream>>>(zc_off, WvT, Voff, BU, nullptr, nullptr);
    gemm_mfma_kernel<<<BS / 64, 128, 0, stream>>>(zc_on, WkT, Kon, BS, fake, ignore);
    gemm_mfma_kernel<<<BS / 64, 128, 0, stream>>>(zc_on, WvT, Von, BS, fake, ignore);

    attn_kernel<<<BS, 64, 0, stream>>>(Qpre, Koff, Voff, Kon, Von, offsets, tokens, AO, S, U);

    gemm_mfma_kernel<<<BS / 64, 128, 0, stream>>>(AO, WoT, (float*)d_out, BS, nullptr, nullptr);
}

// Round 6
// 164.958 us; speedup vs baseline: 12.4652x; 1.0638x over previous
//
#include <hip/hip_runtime.h>
#include <math.h>
#include <float.h>

#define E_DIM 128
typedef unsigned short ushort_t;
typedef __bf16 bf16x8 __attribute__((ext_vector_type(8)));
typedef float  f32x4  __attribute__((ext_vector_type(4)));

__device__ inline ushort_t f2bf(float f) {
    union { float f; unsigned int u; } x; x.f = f;
    unsigned int r = x.u + 0x7fffu + ((x.u >> 16) & 1u);   // RNE
    return (ushort_t)(r >> 16);
}
__device__ inline float bf2f(unsigned int hi16) {
    union { unsigned int u; float f; } x; x.u = hi16 << 16;
    return x.f;
}
__device__ inline void lexmin(float& d, int& i, float d2, int i2) {
    if (d2 < d || (d2 == d && i2 < i)) { d = d2; i = i2; }
}

// ---------------------------------------------------------------------------
// 0) transpose weights to bf16 n-major: Wt[n][k] = bf16(W[k][n])
// ---------------------------------------------------------------------------
__global__ void prep_wt_kernel(const float* __restrict__ Wq, const float* __restrict__ Wk,
                               const float* __restrict__ Wv, const float* __restrict__ Wo,
                               ushort_t* __restrict__ WqT, ushort_t* __restrict__ WkT,
                               ushort_t* __restrict__ WvT, ushort_t* __restrict__ WoT) {
    int idx = blockIdx.x * blockDim.x + threadIdx.x;
    int w = idx >> 14;
    int rem = idx & 16383;
    int k = rem >> 7;
    int n = rem & 127;
    const float* src = (w == 0) ? Wq : (w == 1) ? Wk : (w == 2) ? Wv : Wo;
    ushort_t* dst = (w == 0) ? WqT : (w == 1) ? WkT : (w == 2) ? WvT : WoT;
    dst[n * E_DIM + k] = f2bf(src[k * E_DIM + n]);
}

// ---------------------------------------------------------------------------
// 1) nearest grid cell (L1 argmin, first-min tie-break)
// ---------------------------------------------------------------------------
__global__ void nearest_kernel(const float* __restrict__ xc_off, const float* __restrict__ xc_on,
                               int* __restrict__ nearest, int* __restrict__ counts, int U, int S) {
    __shared__ float4 on[2048];
    __shared__ float sh_d[16][32];
    __shared__ int   sh_i[16][32];
    int b = blockIdx.y;
    const float4* onb = (const float4*)(xc_on + (size_t)b * S * 2);
    for (int i = threadIdx.x; i < S / 2; i += blockDim.x) on[i] = onb[i];
    __syncthreads();
    int part = threadIdx.x >> 4;
    int ug   = threadIdx.x & 15;
    int u0 = blockIdx.x * 32 + ug * 2;
    const float2* offb = (const float2*)(xc_off + (size_t)b * U * 2);
    float2 pA = offb[u0], pB = offb[u0 + 1];
    int h0 = part * (S / 32);
    int h1 = h0 + (S / 32);
    float dA0 = FLT_MAX, dA1 = FLT_MAX, dB0 = FLT_MAX, dB1 = FLT_MAX;
    int iA0 = 0, iA1 = 0, iB0 = 0, iB1 = 0;
    for (int h = h0; h < h1; ++h) {
        float4 cc = on[h];
        int s = h * 2;
        float a0 = fabsf(pA.x - cc.x) + fabsf(pA.y - cc.y);
        float a1 = fabsf(pA.x - cc.z) + fabsf(pA.y - cc.w);
        float b0 = fabsf(pB.x - cc.x) + fabsf(pB.y - cc.y);
        float b1 = fabsf(pB.x - cc.z) + fabsf(pB.y - cc.w);
        if (a0 < dA0) { dA0 = a0; iA0 = s; }
        if (a1 < dA1) { dA1 = a1; iA1 = s + 1; }
        if (b0 < dB0) { dB0 = b0; iB0 = s; }
        if (b1 < dB1) { dB1 = b1; iB1 = s + 1; }
    }
    lexmin(dA0, iA0, dA1, iA1);
    lexmin(dB0, iB0, dB1, iB1);
    sh_d[part][ug * 2] = dA0;     sh_i[part][ug * 2] = iA0;
    sh_d[part][ug * 2 + 1] = dB0; sh_i[part][ug * 2 + 1] = iB0;
    __syncthreads();
    if (threadIdx.x < 32) {
        int ul = threadIdx.x;
        float d = sh_d[0][ul]; int i = sh_i[0][ul];
#pragma unroll
        for (int p = 1; p < 16; ++p) lexmin(d, i, sh_d[p][ul], sh_i[p][ul]);
        int u = blockIdx.x * 32 + ul;
        nearest[b * U + u] = i;
        atomicAdd(&counts[b * S + i], 1);
    }
}

// ---------------------------------------------------------------------------
// 2) exclusive scan of counts -> CSR offsets (single block)
// ---------------------------------------------------------------------------
__global__ void scan_kernel(const int* __restrict__ counts, int* __restrict__ offsets, int N) {
    __shared__ int part[1024];
    const int ITEMS = 16;
    int tid = threadIdx.x;
    int base = tid * ITEMS;
    int local[ITEMS];
    int sum = 0;
    for (int i = 0; i < ITEMS; ++i) {
        int idx = base + i;
        int v = (idx < N) ? counts[idx] : 0;
        local[i] = sum;
        sum += v;
    }
    part[tid] = sum;
    __syncthreads();
    for (int off = 1; off < 1024; off <<= 1) {
        int v = (tid >= off) ? part[tid - off] : 0;
        __syncthreads();
        part[tid] += v;
        __syncthreads();
    }
    int prev = (tid == 0) ? 0 : part[tid - 1];
    for (int i = 0; i < ITEMS; ++i) {
        int idx = base + i;
        if (idx < N) offsets[idx] = prev + local[i];
    }
    if (tid == blockDim.x - 1) offsets[N] = part[tid];
}

// ---------------------------------------------------------------------------
// 3) fill CSR token lists
// ---------------------------------------------------------------------------
__global__ void fill_kernel(const int* __restrict__ nearest, const int* __restrict__ offsets,
                            int* __restrict__ cursor, int* __restrict__ tokens,
                            int BU, int U, int S) {
    int i = blockIdx.x * blockDim.x + threadIdx.x;
    if (i >= BU) return;
    int b = i / U;
    int u = i - b * U;
    int c = b * S + nearest[i];
    int pos = offsets[c] + atomicAdd(&cursor[c], 1);
    tokens[pos] = u;
}

// ---------------------------------------------------------------------------
// 4a) MFMA GEMM, fp32 A in, bf16 out (Q projection)
// ---------------------------------------------------------------------------
__global__ __launch_bounds__(128) void gemmQ_kernel(
        const float* __restrict__ A, const ushort_t* __restrict__ Wt,
        ushort_t* __restrict__ C, int M) {
    __shared__ ushort_t Asm[64 * E_DIM];
    __shared__ ushort_t Wsm[E_DIM * E_DIM];
    const int tid = threadIdx.x;
    const int lane = tid & 63;
    const int wv = tid >> 6;
    const int row0 = blockIdx.x * 64;

    {
        const float* abase = A + (size_t)(row0 + wv * 32) * E_DIM;
#pragma unroll
        for (int i = 0; i < 16; ++i) {
            int e = (lane + i * 64) * 4;
            int r = wv * 32 + (e >> 7);
            int c = e & 127;
            float4 v = *(const float4*)(abase + e);
            unsigned int lo = (unsigned int)f2bf(v.x) | ((unsigned int)f2bf(v.y) << 16);
            unsigned int hi = (unsigned int)f2bf(v.z) | ((unsigned int)f2bf(v.w) << 16);
            int byte = (c * 2) ^ ((r & 7) << 4);
            *(uint2*)((char*)Asm + r * 256 + byte) = make_uint2(lo, hi);
        }
#pragma unroll
        for (int i = 0; i < 16; ++i) {
            int gb = (wv * 1024 + i * 64 + lane) * 16;
            int n = gb >> 8;
            int cb = gb & 255;
            uint4 v = *(const uint4*)((const char*)Wt + gb);
            *(uint4*)((char*)Wsm + n * 256 + (cb ^ ((n & 7) << 4))) = v;
        }
    }
    __syncthreads();

    const int l15 = lane & 15;
    const int kg = lane >> 4;
    f32x4 zz = {0.f, 0.f, 0.f, 0.f};
    f32x4 acc[2][8];
#pragma unroll
    for (int mi = 0; mi < 2; ++mi)
#pragma unroll
        for (int nf = 0; nf < 8; ++nf) acc[mi][nf] = zz;

#pragma unroll
    for (int kc = 0; kc < 4; ++kc) {
        int kb = (kc * 32 + kg * 8) * 2;
        int r0 = wv * 32 + l15;
        int r1 = r0 + 16;
        bf16x8 a0 = *(const bf16x8*)((char*)Asm + r0 * 256 + (kb ^ ((r0 & 7) << 4)));
        bf16x8 a1 = *(const bf16x8*)((char*)Asm + r1 * 256 + (kb ^ ((r1 & 7) << 4)));
#pragma unroll
        for (int nf = 0; nf < 8; ++nf) {
            int n = nf * 16 + l15;
            bf16x8 b = *(const bf16x8*)((char*)Wsm + n * 256 + (kb ^ ((n & 7) << 4)));
            acc[0][nf] = __builtin_amdgcn_mfma_f32_16x16x32_bf16(a0, b, acc[0][nf], 0, 0, 0);
            acc[1][nf] = __builtin_amdgcn_mfma_f32_16x16x32_bf16(a1, b, acc[1][nf], 0, 0, 0);
        }
    }
    const int orow = kg * 4;
#pragma unroll
    for (int mi = 0; mi < 2; ++mi) {
        int rbase = row0 + wv * 32 + mi * 16 + orow;
#pragma unroll
        for (int r = 0; r < 4; ++r) {
            ushort_t* dst = C + (size_t)(rbase + r) * E_DIM + l15;
#pragma unroll
            for (int nf = 0; nf < 8; ++nf) dst[nf * 16] = f2bf(acc[mi][nf][r]);
        }
    }
}

// ---------------------------------------------------------------------------
// 4b) dual-weight MFMA GEMM, fp32 A in, 2x bf16 out (K and V together)
// ---------------------------------------------------------------------------
__global__ __launch_bounds__(128) void gemm2_kernel(
        const float* __restrict__ A,
        const ushort_t* __restrict__ Wt0, const ushort_t* __restrict__ Wt1,
        ushort_t* __restrict__ C0, ushort_t* __restrict__ C1, int M,
        const float* __restrict__ fake, const int* __restrict__ ignore_flag) {
    __shared__ ushort_t Asm[64 * E_DIM];       // 16 KB
    __shared__ ushort_t Wsm0[E_DIM * E_DIM];   // 32 KB
    __shared__ ushort_t Wsm1[E_DIM * E_DIM];   // 32 KB
    const int tid = threadIdx.x;
    const int lane = tid & 63;
    const int wv = tid >> 6;
    const int row0 = blockIdx.x * 64;
    const bool ign = (fake != nullptr) && (*ignore_flag != 0);

    {
        const float* abase = A + (size_t)(row0 + wv * 32) * E_DIM;
#pragma unroll
        for (int i = 0; i < 16; ++i) {
            int e = (lane + i * 64) * 4;
            int r = wv * 32 + (e >> 7);
            int c = e & 127;
            float4 v = *(const float4*)(ign ? (fake + c) : (abase + e));
            unsigned int lo = (unsigned int)f2bf(v.x) | ((unsigned int)f2bf(v.y) << 16);
            unsigned int hi = (unsigned int)f2bf(v.z) | ((unsigned int)f2bf(v.w) << 16);
            int byte = (c * 2) ^ ((r & 7) << 4);
            *(uint2*)((char*)Asm + r * 256 + byte) = make_uint2(lo, hi);
        }
        const ushort_t* wsrc = wv ? Wt1 : Wt0;
        ushort_t* wdst = wv ? Wsm1 : Wsm0;
#pragma unroll
        for (int i = 0; i < 32; ++i) {
            int gb = (i * 64 + lane) * 16;
            int n = gb >> 8;
            int cb = gb & 255;
            uint4 v = *(const uint4*)((const char*)wsrc + gb);
            *(uint4*)((char*)wdst + n * 256 + (cb ^ ((n & 7) << 4))) = v;
        }
    }
    __syncthreads();

    const int l15 = lane & 15;
    const int kg = lane >> 4;
    f32x4 zz = {0.f, 0.f, 0.f, 0.f};
    f32x4 acc0[2][8], acc1[2][8];
#pragma unroll
    for (int mi = 0; mi < 2; ++mi)
#pragma unroll
        for (int nf = 0; nf < 8; ++nf) { acc0[mi][nf] = zz; acc1[mi][nf] = zz; }

#pragma unroll
    for (int kc = 0; kc < 4; ++kc) {
        int kb = (kc * 32 + kg * 8) * 2;
        int r0 = wv * 32 + l15;
        int r1 = r0 + 16;
        bf16x8 a0 = *(const bf16x8*)((char*)Asm + r0 * 256 + (kb ^ ((r0 & 7) << 4)));
        bf16x8 a1 = *(const bf16x8*)((char*)Asm + r1 * 256 + (kb ^ ((r1 & 7) << 4)));
#pragma unroll
        for (int nf = 0; nf < 8; ++nf) {
            int n = nf * 16 + l15;
            int nb = n * 256 + (kb ^ ((n & 7) << 4));
            bf16x8 b0 = *(const bf16x8*)((char*)Wsm0 + nb);
            acc0[0][nf] = __builtin_amdgcn_mfma_f32_16x16x32_bf16(a0, b0, acc0[0][nf], 0, 0, 0);
            acc0[1][nf] = __builtin_amdgcn_mfma_f32_16x16x32_bf16(a1, b0, acc0[1][nf], 0, 0, 0);
            bf16x8 b1 = *(const bf16x8*)((char*)Wsm1 + nb);
            acc1[0][nf] = __builtin_amdgcn_mfma_f32_16x16x32_bf16(a0, b1, acc1[0][nf], 0, 0, 0);
            acc1[1][nf] = __builtin_amdgcn_mfma_f32_16x16x32_bf16(a1, b1, acc1[1][nf], 0, 0, 0);
        }
    }
    const int orow = kg * 4;
#pragma unroll
    for (int mi = 0; mi < 2; ++mi) {
        int rbase = row0 + wv * 32 + mi * 16 + orow;
#pragma unroll
        for (int r = 0; r < 4; ++r) {
            ushort_t* d0 = C0 + (size_t)(rbase + r) * E_DIM + l15;
            ushort_t* d1 = C1 + (size_t)(rbase + r) * E_DIM + l15;
#pragma unroll
            for (int nf = 0; nf < 8; ++nf) {
                d0[nf * 16] = f2bf(acc0[mi][nf][r]);
                d1[nf * 16] = f2bf(acc1[mi][nf][r]);
            }
        }
    }
}

// ---------------------------------------------------------------------------
// 4c) MFMA GEMM, bf16 A in, fp32 out (output projection)
// ---------------------------------------------------------------------------
__global__ __launch_bounds__(128) void gemmO_kernel(
        const ushort_t* __restrict__ A, const ushort_t* __restrict__ Wt,
        float* __restrict__ C, int M) {
    __shared__ ushort_t Asm[64 * E_DIM];
    __shared__ ushort_t Wsm[E_DIM * E_DIM];
    const int tid = threadIdx.x;
    const int lane = tid & 63;
    const int wv = tid >> 6;
    const int row0 = blockIdx.x * 64;

    {
        const char* abase = (const char*)(A + (size_t)(row0 + wv * 32) * E_DIM);
#pragma unroll
        for (int i = 0; i < 8; ++i) {
            int gb = (lane + i * 64) * 16;          // byte in wave's 8 KB chunk
            int r = wv * 32 + (gb >> 8);
            int cb = gb & 255;
            uint4 v = *(const uint4*)(abase + gb);
            *(uint4*)((char*)Asm + r * 256 + (cb ^ ((r & 7) << 4))) = v;
        }
#pragma unroll
        for (int i = 0; i < 16; ++i) {
            int gb = (wv * 1024 + i * 64 + lane) * 16;
            int n = gb >> 8;
            int cb = gb & 255;
            uint4 v = *(const uint4*)((const char*)Wt + gb);
            *(uint4*)((char*)Wsm + n * 256 + (cb ^ ((n & 7) << 4))) = v;
        }
    }
    __syncthreads();

    const int l15 = lane & 15;
    const int kg = lane >> 4;
    f32x4 zz = {0.f, 0.f, 0.f, 0.f};
    f32x4 acc[2][8];
#pragma unroll
    for (int mi = 0; mi < 2; ++mi)
#pragma unroll
        for (int nf = 0; nf < 8; ++nf) acc[mi][nf] = zz;

#pragma unroll
    for (int kc = 0; kc < 4; ++kc) {
        int kb = (kc * 32 + kg * 8) * 2;
        int r0 = wv * 32 + l15;
        int r1 = r0 + 16;
        bf16x8 a0 = *(const bf16x8*)((char*)Asm + r0 * 256 + (kb ^ ((r0 & 7) << 4)));
        bf16x8 a1 = *(const bf16x8*)((char*)Asm + r1 * 256 + (kb ^ ((r1 & 7) << 4)));
#pragma unroll
        for (int nf = 0; nf < 8; ++nf) {
            int n = nf * 16 + l15;
            bf16x8 b = *(const bf16x8*)((char*)Wsm + n * 256 + (kb ^ ((n & 7) << 4)));
            acc[0][nf] = __builtin_amdgcn_mfma_f32_16x16x32_bf16(a0, b, acc[0][nf], 0, 0, 0);
            acc[1][nf] = __builtin_amdgcn_mfma_f32_16x16x32_bf16(a1, b, acc[1][nf], 0, 0, 0);
        }
    }
    const int orow = kg * 4;
#pragma unroll
    for (int mi = 0; mi < 2; ++mi) {
        int rbase = row0 + wv * 32 + mi * 16 + orow;
#pragma unroll
        for (int r = 0; r < 4; ++r) {
            float* dst = C + (size_t)(rbase + r) * E_DIM + l15;
#pragma unroll
            for (int nf = 0; nf < 8; ++nf) dst[nf * 16] = acc[mi][nf][r];
        }
    }
}

// ---------------------------------------------------------------------------
// 5) per-cell masked MHA. Lane l owns elems {2l, 2l+1} (head = l>>3);
//    coalesced uint loads, width-8 reduce, on-grid token as initializer.
//    4 cells per 256-thread block (1 wave per cell).
// ---------------------------------------------------------------------------
__global__ void attn_kernel(const ushort_t* __restrict__ Qpre,
                            const ushort_t* __restrict__ Koff, const ushort_t* __restrict__ Voff,
                            const ushort_t* __restrict__ Kon, const ushort_t* __restrict__ Von,
                            const int* __restrict__ offsets, const int* __restrict__ tokens,
                            ushort_t* __restrict__ AO, int S, int U) {
    int wv = threadIdx.x >> 6;
    int lane = threadIdx.x & 63;
    int c = blockIdx.x * 4 + wv;
    int b = c / S;
    int cl = c - b * S;

    unsigned int qw = ((const unsigned int*)(Qpre + (size_t)cl * E_DIM))[lane];
    float q0 = bf2f(qw & 0xffffu) * 0.25f;       // scale 1/sqrt(16) folded in
    float q1 = bf2f(qw >> 16) * 0.25f;

    // init with the always-valid on-grid token
    unsigned int kw = ((const unsigned int*)(Kon + (size_t)c * E_DIM))[lane];
    float p = q0 * bf2f(kw & 0xffffu) + q1 * bf2f(kw >> 16);
    p += __shfl_xor(p, 4, 8);
    p += __shfl_xor(p, 2, 8);
    p += __shfl_xor(p, 1, 8);
    unsigned int vw = ((const unsigned int*)(Von + (size_t)c * E_DIM))[lane];
    float mm = p, ll = 1.f;
    float o0 = bf2f(vw & 0xffffu), o1 = bf2f(vw >> 16);

    int beg = offsets[c], end = offsets[c + 1];
    for (int t = beg; t < end; ++t) {
        int u = tokens[t];
        size_t rr = ((size_t)b * U + u) * E_DIM;
        unsigned int kw2 = ((const unsigned int*)(Koff + rr))[lane];
        unsigned int vw2 = ((const unsigned int*)(Voff + rr))[lane];
        float p2 = q0 * bf2f(kw2 & 0xffffu) + q1 * bf2f(kw2 >> 16);
        p2 += __shfl_xor(p2, 4, 8);
        p2 += __shfl_xor(p2, 2, 8);
        p2 += __shfl_xor(p2, 1, 8);
        float v0 = bf2f(vw2 & 0xffffu), v1 = bf2f(vw2 >> 16);
        float nm = fmaxf(mm, p2);
        float f = __expf(mm - nm), w = __expf(p2 - nm);
        ll = ll * f + w;
        o0 = o0 * f + w * v0;
        o1 = o1 * f + w * v1;
        mm = nm;
    }
    float inv = 1.f / ll;
    unsigned int out = (unsigned int)f2bf(o0 * inv) | ((unsigned int)f2bf(o1 * inv) << 16);
    ((unsigned int*)(AO + (size_t)c * E_DIM))[lane] = out;
}

// ---------------------------------------------------------------------------
extern "C" void kernel_launch(void* const* d_in, const int* in_sizes, int n_in,
                              void* d_out, int out_size, void* d_ws, size_t ws_size,
                              hipStream_t stream) {
    const float* xc_off  = (const float*)d_in[0];
    const float* xc_on   = (const float*)d_in[1];
    const float* zc_off  = (const float*)d_in[2];
    const float* zc_on   = (const float*)d_in[3];
    const float* latents = (const float*)d_in[4];
    const float* fake    = (const float*)d_in[5];
    const float* Wq      = (const float*)d_in[6];
    const float* Wk      = (const float*)d_in[7];
    const float* Wv      = (const float*)d_in[8];
    const float* Wo      = (const float*)d_in[9];
    const int*   ignore  = (const int*)d_in[10];

    const int E = in_sizes[5];              // 128
    const int S = in_sizes[4] / E;          // 4096
    const int B = in_sizes[1] / (S * 2);    // 4
    const int U = in_sizes[0] / (B * 2);    // 4096
    const int BS = B * S, BU = B * U;

    char* ws = (char*)d_ws;
    size_t off = 0;
    auto alloc = [&](size_t bytes) {
        size_t r = off;
        off += (bytes + 255) & ~(size_t)255;
        return r;
    };
    int*   counts  = (int*)(ws + alloc((size_t)BS * 4));      // contiguous with cursor
    int*   cursor  = (int*)(ws + alloc((size_t)BS * 4));
    int*   nearest = (int*)(ws + alloc((size_t)BU * 4));
    int*   offsets = (int*)(ws + alloc((size_t)(BS + 1) * 4));
    int*   tokens  = (int*)(ws + alloc((size_t)BU * 4));
    ushort_t* Qpre = (ushort_t*)(ws + alloc((size_t)S * E * 2));
    ushort_t* Koff = (ushort_t*)(ws + alloc((size_t)BU * E * 2));
    ushort_t* Voff = (ushort_t*)(ws + alloc((size_t)BU * E * 2));
    ushort_t* Kon  = (ushort_t*)(ws + alloc((size_t)BS * E * 2));
    ushort_t* Von  = (ushort_t*)(ws + alloc((size_t)BS * E * 2));
    ushort_t* AO   = (ushort_t*)(ws + alloc((size_t)BS * E * 2));
    ushort_t* WqT  = (ushort_t*)(ws + alloc((size_t)E * E * 2));
    ushort_t* WkT  = (ushort_t*)(ws + alloc((size_t)E * E * 2));
    ushort_t* WvT  = (ushort_t*)(ws + alloc((size_t)E * E * 2));
    ushort_t* WoT  = (ushort_t*)(ws + alloc((size_t)E * E * 2));

    hipMemsetAsync(counts, 0, (size_t)BS * 8, stream);   // counts + cursor (contiguous)

    prep_wt_kernel<<<(4 * E * E) / 256, 256, 0, stream>>>(Wq, Wk, Wv, Wo, WqT, WkT, WvT, WoT);

    dim3 ngrid(U / 32, B);
    nearest_kernel<<<ngrid, 256, 0, stream>>>(xc_off, xc_on, nearest, counts, U, S);
    scan_kernel<<<1, 1024, 0, stream>>>(counts, offsets, BS);
    fill_kernel<<<(BU + 255) / 256, 256, 0, stream>>>(nearest, offsets, cursor, tokens, BU, U, S);

    gemmQ_kernel<<<S / 64, 128, 0, stream>>>(latents, WqT, Qpre, S);
    gemm2_kernel<<<BU / 64, 128, 0, stream>>>(zc_off, WkT, WvT, Koff, Voff, BU, nullptr, nullptr);
    gemm2_kernel<<<BS / 64, 128, 0, stream>>>(zc_on, WkT, WvT, Kon, Von, BS, fake, ignore);

    attn_kernel<<<BS / 4, 256, 0, stream>>>(Qpre, Koff, Voff, Kon, Von, offsets, tokens, AO, S, U);

    gemmO_kernel<<<BS / 64, 128, 0, stream>>>(AO, WoT, (float*)d_out, BS);
}